// Round 5
// baseline (204.987 us; speedup 1.0000x reference)
//
#include <hip/hip_runtime.h>

#define SP    65536      // 16*64*64 spatial voxels
#define DD    16
#define HH    64
#define WW    64
#define CIN   64
#define COUT  64

// ws layout (fp32): q [64][SP] | k [64][SP] | v [64][SP]   (48 MB total)

// Grid: (SP/128, 3). Block = 256 threads; each thread computes 16 output
// channels for TWO consecutive positions (float2 x / float2 store), so each
// ds_read_b128 of 4 weights feeds 8 FMAs -> VALU-bound instead of LDS-bound.
__global__ __launch_bounds__(256) void proj(const float* __restrict__ x,
                                            const float* __restrict__ wq,
                                            const float* __restrict__ wk,
                                            const float* __restrict__ wv,
                                            float* __restrict__ q,
                                            float* __restrict__ k,
                                            float* __restrict__ v) {
    __shared__ float wlds[COUT * CIN];   // 16 KB
    const int m = blockIdx.y;
    const float* __restrict__ wsel = (m == 0) ? wq : (m == 1) ? wk : wv;
    float* __restrict__       osel = (m == 0) ? q  : (m == 1) ? k  : v;

    // stage weights -> LDS, float4-coalesced
    {
        const float4* src = (const float4*)wsel;
        float4*       dst = (float4*)wlds;
#pragma unroll
        for (int i = 0; i < 4; ++i)
            dst[threadIdx.x + 256 * i] = src[threadIdx.x + 256 * i];
    }
    __syncthreads();

    const int lane = threadIdx.x & 63;
    const int og   = threadIdx.x >> 6;                 // channel quarter 0..3
    const int p    = blockIdx.x * 128 + lane * 2;      // 2 positions/thread

    float2 xv[CIN];                                    // 128 VGPRs
#pragma unroll
    for (int c = 0; c < CIN; ++c)
        xv[c] = *(const float2*)(x + c * SP + p);

#pragma unroll 2
    for (int oo = 0; oo < 16; ++oo) {
        const int o = og * 16 + oo;
        const float4* wrow = (const float4*)(wlds + o * CIN);
        float a0 = 0.f, a1 = 0.f;
#pragma unroll
        for (int c4 = 0; c4 < CIN / 4; ++c4) {
            const float4 w4 = wrow[c4];
            a0 = fmaf(w4.x, xv[4 * c4 + 0].x, a0);
            a1 = fmaf(w4.x, xv[4 * c4 + 0].y, a1);
            a0 = fmaf(w4.y, xv[4 * c4 + 1].x, a0);
            a1 = fmaf(w4.y, xv[4 * c4 + 1].y, a1);
            a0 = fmaf(w4.z, xv[4 * c4 + 2].x, a0);
            a1 = fmaf(w4.z, xv[4 * c4 + 2].y, a1);
            a0 = fmaf(w4.w, xv[4 * c4 + 3].x, a0);
            a1 = fmaf(w4.w, xv[4 * c4 + 3].y, a1);
        }
        *(float2*)(osel + o * SP + p) = make_float2(a0, a1);
    }
}

// attn: 4 consecutive w-positions per thread. Per (kd,kh) row: one aligned
// float4 + two edge scalars for k and for v (6 VMEM vs 24 scalar), window
// values reused from registers across the 4 positions. Single-pass softmax
// (logits bounded, shift-invariant). OOB: k=0+rel stays in softmax, v=0.
template<int AXIS>
__device__ __forceinline__ void attn4(const float* __restrict__ kc,
                                      const float* __restrict__ vc,
                                      const float4 q4,
                                      float r0, float r1, float r2,
                                      int d, int h, int w,
                                      float4& outv) {
    float s[4]  = {0.f, 0.f, 0.f, 0.f};
    float a[4]  = {0.f, 0.f, 0.f, 0.f};
    const float qv[4] = {q4.x, q4.y, q4.z, q4.w};

#pragma unroll
    for (int kd = 0; kd < 3; ++kd) {
#pragma unroll
        for (int kh = 0; kh < 3; ++kh) {
            const int dp = d + kd - 1, hp = h + kh - 1;
            const bool vp = ((unsigned)dp < (unsigned)DD) &&
                            ((unsigned)hp < (unsigned)HH);
            const int roff = (dp * HH + hp) * WW + w;

            float4 km, vm;
            float  kl, kr, vl, vr;
            if (vp) {
                km = *(const float4*)(kc + roff);
                vm = *(const float4*)(vc + roff);
                kl = (w > 0)       ? kc[roff - 1] : 0.f;
                vl = (w > 0)       ? vc[roff - 1] : 0.f;
                kr = (w < WW - 4)  ? kc[roff + 4] : 0.f;
                vr = (w < WW - 4)  ? vc[roff + 4] : 0.f;
            } else {
                km = make_float4(0.f, 0.f, 0.f, 0.f);
                vm = make_float4(0.f, 0.f, 0.f, 0.f);
                kl = kr = vl = vr = 0.f;
            }
            const float kwv[6] = {kl, km.x, km.y, km.z, km.w, kr};
            const float vwv[6] = {vl, vm.x, vm.y, vm.z, vm.w, vr};

            const float rrow = (AXIS == 0) ? ((kd == 0) ? r0 : (kd == 1) ? r1 : r2)
                             : (AXIS == 1) ? ((kh == 0) ? r0 : (kh == 1) ? r1 : r2)
                             : 0.f;
#pragma unroll
            for (int i = 0; i < 4; ++i) {
                const float qi = qv[i];
                const float ra0 = (AXIS == 2) ? r0 : rrow;
                const float ra1 = (AXIS == 2) ? r1 : rrow;
                const float ra2 = (AXIS == 2) ? r2 : rrow;
                const float e0 = __expf(qi * (kwv[i + 0] + ra0));
                const float e1 = __expf(qi * (kwv[i + 1] + ra1));
                const float e2 = __expf(qi * (kwv[i + 2] + ra2));
                s[i] += e0 + e1 + e2;
                a[i] = fmaf(e0, vwv[i + 0], a[i]);
                a[i] = fmaf(e1, vwv[i + 1], a[i]);
                a[i] = fmaf(e2, vwv[i + 2], a[i]);
            }
        }
    }
    outv.x = a[0] * __builtin_amdgcn_rcpf(s[0]);
    outv.y = a[1] * __builtin_amdgcn_rcpf(s[1]);
    outv.z = a[2] * __builtin_amdgcn_rcpf(s[2]);
    outv.w = a[3] * __builtin_amdgcn_rcpf(s[3]);
}

__global__ __launch_bounds__(256) void attn(const float* __restrict__ q,
                                            const float* __restrict__ k,
                                            const float* __restrict__ v,
                                            const float* __restrict__ rel_d,
                                            const float* __restrict__ rel_h,
                                            const float* __restrict__ rel_w,
                                            float* __restrict__ out) {
    const int t = blockIdx.x * 256 + threadIdx.x;   // 0 .. COUT*SP/4-1
    const int o = t >> 14;                           // (t*4) >> 16
    const int p = (t & 16383) * 4;
    const int w = p & 63;
    const int h = (p >> 6) & 63;
    const int d = p >> 12;

    const int ou = __builtin_amdgcn_readfirstlane(o);

    const float4 q4 = *(const float4*)(q + o * SP + p);
    const float* __restrict__ kc = k + o * SP;
    const float* __restrict__ vc = v + o * SP;

    float4 outv;
    if (ou < 21) {
        attn4<0>(kc, vc, q4,
                 rel_d[ou * 3 + 0], rel_d[ou * 3 + 1], rel_d[ou * 3 + 2],
                 d, h, w, outv);
    } else if (ou < 42) {
        const int b = ou - 21;
        attn4<1>(kc, vc, q4,
                 rel_h[b * 3 + 0], rel_h[b * 3 + 1], rel_h[b * 3 + 2],
                 d, h, w, outv);
    } else {
        const int b = ou - 42;
        attn4<2>(kc, vc, q4,
                 rel_w[b * 3 + 0], rel_w[b * 3 + 1], rel_w[b * 3 + 2],
                 d, h, w, outv);
    }
    *(float4*)(out + o * SP + p) = outv;
}

extern "C" void kernel_launch(void* const* d_in, const int* in_sizes, int n_in,
                              void* d_out, int out_size, void* d_ws, size_t ws_size,
                              hipStream_t stream) {
    const float* x     = (const float*)d_in[0];
    const float* w_q   = (const float*)d_in[1];
    const float* w_k   = (const float*)d_in[2];
    const float* w_v   = (const float*)d_in[3];
    const float* rel_d = (const float*)d_in[4];
    const float* rel_h = (const float*)d_in[5];
    const float* rel_w = (const float*)d_in[6];
    float* out = (float*)d_out;

    float* ws = (float*)d_ws;
    float* q  = ws;
    float* k  = ws + (size_t)COUT * SP;
    float* v  = ws + 2 * (size_t)COUT * SP;

    dim3 pgrid(SP / 128, 3);
    proj<<<pgrid, 256, 0, stream>>>(x, w_q, w_k, w_v, q, k, v);
    attn<<<(COUT * SP / 4) / 256, 256, 0, stream>>>(q, k, v, rel_d, rel_h, rel_w, out);
}

// Round 6
// 156.037 us; speedup vs baseline: 1.3137x; 1.3137x over previous
//
#include <hip/hip_runtime.h>

#define SP    65536      // 16*64*64 spatial voxels
#define DD    16
#define HH    64
#define WW    64
#define CIN   64
#define COUT  64

#define XPAD  68         // LDS row pitch (floats): 64 + 4 -> 2-way-max bank aliasing, 16B aligned

// ws layout (fp32): q [64][SP] | k [64][SP] | v [64][SP]   (48 MB total)

// proj as a proper LDS GEMM. Grid: SP/64 blocks; block = 256 threads
// computes q,k,v (sequentially, reusing the x tile) for 64 positions x 64
// output channels. LDS: x tile [64c][64p] (17 KB) + w [64o][64c] (17 KB,
// restaged per matrix) = 34 KB -> 4 blocks/CU. Thread tile 4o x 4p: per
// c4-step 8 ds_read_b128 feed 64 FMAs (128 VALU cyc vs ~96 LDS cyc) ->
// VALU-bound, unlike the previous 1:1.5 ratio. VGPR ~80 keeps occupancy up
// (round-5's float2-in-VGPR attempt hit 152 VGPR, 25% VALUBusy).
__global__ __launch_bounds__(256) void proj(const float* __restrict__ x,
                                            const float* __restrict__ wq,
                                            const float* __restrict__ wk,
                                            const float* __restrict__ wv,
                                            float* __restrict__ q,
                                            float* __restrict__ k,
                                            float* __restrict__ v) {
    __shared__ float xl[CIN][XPAD];    // [c][p]
    __shared__ float wl[COUT][XPAD];   // [o][c]

    const int t  = threadIdx.x;
    const int p0 = blockIdx.x * 64;

    // stage x tile: 64c x 64p = 1024 float4; 4 per thread, coalesced per c-row
#pragma unroll
    for (int i = 0; i < 4; ++i) {
        const int f = t + 256 * i;        // 0..1023
        const int c = f >> 4, j = f & 15; // j: float4 index within row
        const float4 val = *(const float4*)(x + c * SP + p0 + j * 4);
        *(float4*)(&xl[c][j * 4]) = val;
    }

    const int og    = t >> 4;        // 0..15
    const int pg    = t & 15;        // 0..15
    const int obase = og * 4;
    const int pbase = pg * 4;

#pragma unroll 1
    for (int m = 0; m < 3; ++m) {
        const float* __restrict__ wsel = (m == 0) ? wq : (m == 1) ? wk : wv;
        float* __restrict__       osel = (m == 0) ? q  : (m == 1) ? k  : v;

        __syncthreads();   // protects wl (prev iter) and, at m=0, xl staging
#pragma unroll
        for (int i = 0; i < 4; ++i) {
            const int f = t + 256 * i;
            const int o = f >> 4, j = f & 15;
            const float4 val = *(const float4*)(wsel + o * CIN + j * 4);
            *(float4*)(&wl[o][j * 4]) = val;
        }
        __syncthreads();

        float acc[4][4] = {};
#pragma unroll
        for (int c4 = 0; c4 < CIN / 4; ++c4) {
            float4 w4[4], x4[4];
#pragma unroll
            for (int i = 0; i < 4; ++i)
                w4[i] = *(const float4*)(&wl[obase + i][c4 * 4]);
#pragma unroll
            for (int cc = 0; cc < 4; ++cc)
                x4[cc] = *(const float4*)(&xl[c4 * 4 + cc][pbase]);
#pragma unroll
            for (int i = 0; i < 4; ++i) {
                acc[i][0] = fmaf(w4[i].x, x4[0].x, acc[i][0]);
                acc[i][1] = fmaf(w4[i].x, x4[0].y, acc[i][1]);
                acc[i][2] = fmaf(w4[i].x, x4[0].z, acc[i][2]);
                acc[i][3] = fmaf(w4[i].x, x4[0].w, acc[i][3]);
                acc[i][0] = fmaf(w4[i].y, x4[1].x, acc[i][0]);
                acc[i][1] = fmaf(w4[i].y, x4[1].y, acc[i][1]);
                acc[i][2] = fmaf(w4[i].y, x4[1].z, acc[i][2]);
                acc[i][3] = fmaf(w4[i].y, x4[1].w, acc[i][3]);
                acc[i][0] = fmaf(w4[i].z, x4[2].x, acc[i][0]);
                acc[i][1] = fmaf(w4[i].z, x4[2].y, acc[i][1]);
                acc[i][2] = fmaf(w4[i].z, x4[2].z, acc[i][2]);
                acc[i][3] = fmaf(w4[i].z, x4[2].w, acc[i][3]);
                acc[i][0] = fmaf(w4[i].w, x4[3].x, acc[i][0]);
                acc[i][1] = fmaf(w4[i].w, x4[3].y, acc[i][1]);
                acc[i][2] = fmaf(w4[i].w, x4[3].z, acc[i][2]);
                acc[i][3] = fmaf(w4[i].w, x4[3].w, acc[i][3]);
            }
        }

#pragma unroll
        for (int i = 0; i < 4; ++i) {
            const float4 st = make_float4(acc[i][0], acc[i][1], acc[i][2], acc[i][3]);
            *(float4*)(osel + (obase + i) * SP + p0 + pbase) = st;
        }
    }
}

// attn: 4 consecutive w-positions per thread. Per (kd,kh) row: one aligned
// float4 + two edge scalars for k and for v, window values reused from
// registers across the 4 positions. Single-pass softmax (logits bounded,
// shift-invariant). OOB: k=0+rel stays in softmax, v=0.
template<int AXIS>
__device__ __forceinline__ void attn4(const float* __restrict__ kc,
                                      const float* __restrict__ vc,
                                      const float4 q4,
                                      float r0, float r1, float r2,
                                      int d, int h, int w,
                                      float4& outv) {
    float s[4]  = {0.f, 0.f, 0.f, 0.f};
    float a[4]  = {0.f, 0.f, 0.f, 0.f};
    const float qv[4] = {q4.x, q4.y, q4.z, q4.w};

#pragma unroll
    for (int kd = 0; kd < 3; ++kd) {
#pragma unroll
        for (int kh = 0; kh < 3; ++kh) {
            const int dp = d + kd - 1, hp = h + kh - 1;
            const bool vp = ((unsigned)dp < (unsigned)DD) &&
                            ((unsigned)hp < (unsigned)HH);
            const int roff = (dp * HH + hp) * WW + w;

            float4 km, vm;
            float  kl, kr, vl, vr;
            if (vp) {
                km = *(const float4*)(kc + roff);
                vm = *(const float4*)(vc + roff);
                kl = (w > 0)       ? kc[roff - 1] : 0.f;
                vl = (w > 0)       ? vc[roff - 1] : 0.f;
                kr = (w < WW - 4)  ? kc[roff + 4] : 0.f;
                vr = (w < WW - 4)  ? vc[roff + 4] : 0.f;
            } else {
                km = make_float4(0.f, 0.f, 0.f, 0.f);
                vm = make_float4(0.f, 0.f, 0.f, 0.f);
                kl = kr = vl = vr = 0.f;
            }
            const float kwv[6] = {kl, km.x, km.y, km.z, km.w, kr};
            const float vwv[6] = {vl, vm.x, vm.y, vm.z, vm.w, vr};

            const float rrow = (AXIS == 0) ? ((kd == 0) ? r0 : (kd == 1) ? r1 : r2)
                             : (AXIS == 1) ? ((kh == 0) ? r0 : (kh == 1) ? r1 : r2)
                             : 0.f;
#pragma unroll
            for (int i = 0; i < 4; ++i) {
                const float qi = qv[i];
                const float ra0 = (AXIS == 2) ? r0 : rrow;
                const float ra1 = (AXIS == 2) ? r1 : rrow;
                const float ra2 = (AXIS == 2) ? r2 : rrow;
                const float e0 = __expf(qi * (kwv[i + 0] + ra0));
                const float e1 = __expf(qi * (kwv[i + 1] + ra1));
                const float e2 = __expf(qi * (kwv[i + 2] + ra2));
                s[i] += e0 + e1 + e2;
                a[i] = fmaf(e0, vwv[i + 0], a[i]);
                a[i] = fmaf(e1, vwv[i + 1], a[i]);
                a[i] = fmaf(e2, vwv[i + 2], a[i]);
            }
        }
    }
    outv.x = a[0] * __builtin_amdgcn_rcpf(s[0]);
    outv.y = a[1] * __builtin_amdgcn_rcpf(s[1]);
    outv.z = a[2] * __builtin_amdgcn_rcpf(s[2]);
    outv.w = a[3] * __builtin_amdgcn_rcpf(s[3]);
}

__global__ __launch_bounds__(256) void attn(const float* __restrict__ q,
                                            const float* __restrict__ k,
                                            const float* __restrict__ v,
                                            const float* __restrict__ rel_d,
                                            const float* __restrict__ rel_h,
                                            const float* __restrict__ rel_w,
                                            float* __restrict__ out) {
    const int t = blockIdx.x * 256 + threadIdx.x;   // 0 .. COUT*SP/4-1
    const int o = t >> 14;                           // (t*4) >> 16
    const int p = (t & 16383) * 4;
    const int w = p & 63;
    const int h = (p >> 6) & 63;
    const int d = p >> 12;

    const int ou = __builtin_amdgcn_readfirstlane(o);

    const float4 q4 = *(const float4*)(q + o * SP + p);
    const float* __restrict__ kc = k + o * SP;
    const float* __restrict__ vc = v + o * SP;

    float4 outv;
    if (ou < 21) {
        attn4<0>(kc, vc, q4,
                 rel_d[ou * 3 + 0], rel_d[ou * 3 + 1], rel_d[ou * 3 + 2],
                 d, h, w, outv);
    } else if (ou < 42) {
        const int b = ou - 21;
        attn4<1>(kc, vc, q4,
                 rel_h[b * 3 + 0], rel_h[b * 3 + 1], rel_h[b * 3 + 2],
                 d, h, w, outv);
    } else {
        const int b = ou - 42;
        attn4<2>(kc, vc, q4,
                 rel_w[b * 3 + 0], rel_w[b * 3 + 1], rel_w[b * 3 + 2],
                 d, h, w, outv);
    }
    *(float4*)(out + o * SP + p) = outv;
}

extern "C" void kernel_launch(void* const* d_in, const int* in_sizes, int n_in,
                              void* d_out, int out_size, void* d_ws, size_t ws_size,
                              hipStream_t stream) {
    const float* x     = (const float*)d_in[0];
    const float* w_q   = (const float*)d_in[1];
    const float* w_k   = (const float*)d_in[2];
    const float* w_v   = (const float*)d_in[3];
    const float* rel_d = (const float*)d_in[4];
    const float* rel_h = (const float*)d_in[5];
    const float* rel_w = (const float*)d_in[6];
    float* out = (float*)d_out;

    float* ws = (float*)d_ws;
    float* q  = ws;
    float* k  = ws + (size_t)COUT * SP;
    float* v  = ws + 2 * (size_t)COUT * SP;

    proj<<<SP / 64, 256, 0, stream>>>(x, w_q, w_k, w_v, q, k, v);
    attn<<<(COUT * SP / 4) / 256, 256, 0, stream>>>(q, k, v, rel_d, rel_h, rel_w, out);
}

// Round 7
// 153.910 us; speedup vs baseline: 1.3319x; 1.0138x over previous
//
#include <hip/hip_runtime.h>

#define SP    65536      // 16*64*64 spatial voxels
#define DD    16
#define HH    64
#define WW    64
#define CIN   64
#define COUT  64

#define XPAD  68         // proj LDS row pitch

// ws layout (fp32): q [64][SP] | k [64][SP] | v [64][SP]   (48 MB total)

// proj: LDS GEMM (unchanged from round 6). Block = 64 pos x 64 ch, thread
// tile 4o x 4p, q/k/v sequentially reusing the x tile.
__global__ __launch_bounds__(256) void proj(const float* __restrict__ x,
                                            const float* __restrict__ wq,
                                            const float* __restrict__ wk,
                                            const float* __restrict__ wv,
                                            float* __restrict__ q,
                                            float* __restrict__ k,
                                            float* __restrict__ v) {
    __shared__ float xl[CIN][XPAD];    // [c][p]
    __shared__ float wl[COUT][XPAD];   // [o][c]

    const int t  = threadIdx.x;
    const int p0 = blockIdx.x * 64;

#pragma unroll
    for (int i = 0; i < 4; ++i) {
        const int f = t + 256 * i;
        const int c = f >> 4, j = f & 15;
        const float4 val = *(const float4*)(x + c * SP + p0 + j * 4);
        *(float4*)(&xl[c][j * 4]) = val;
    }

    const int og    = t >> 4;
    const int pg    = t & 15;
    const int obase = og * 4;
    const int pbase = pg * 4;

#pragma unroll 1
    for (int m = 0; m < 3; ++m) {
        const float* __restrict__ wsel = (m == 0) ? wq : (m == 1) ? wk : wv;
        float* __restrict__       osel = (m == 0) ? q  : (m == 1) ? k  : v;

        __syncthreads();
#pragma unroll
        for (int i = 0; i < 4; ++i) {
            const int f = t + 256 * i;
            const int o = f >> 4, j = f & 15;
            const float4 val = *(const float4*)(wsel + o * CIN + j * 4);
            *(float4*)(&wl[o][j * 4]) = val;
        }
        __syncthreads();

        float acc[4][4] = {};
#pragma unroll
        for (int c4 = 0; c4 < CIN / 4; ++c4) {
            float4 w4[4], x4[4];
#pragma unroll
            for (int i = 0; i < 4; ++i)
                w4[i] = *(const float4*)(&wl[obase + i][c4 * 4]);
#pragma unroll
            for (int cc = 0; cc < 4; ++cc)
                x4[cc] = *(const float4*)(&xl[c4 * 4 + cc][pbase]);
#pragma unroll
            for (int i = 0; i < 4; ++i) {
                acc[i][0] = fmaf(w4[i].x, x4[0].x, acc[i][0]);
                acc[i][1] = fmaf(w4[i].x, x4[0].y, acc[i][1]);
                acc[i][2] = fmaf(w4[i].x, x4[0].z, acc[i][2]);
                acc[i][3] = fmaf(w4[i].x, x4[0].w, acc[i][3]);
                acc[i][0] = fmaf(w4[i].y, x4[1].x, acc[i][0]);
                acc[i][1] = fmaf(w4[i].y, x4[1].y, acc[i][1]);
                acc[i][2] = fmaf(w4[i].y, x4[1].z, acc[i][2]);
                acc[i][3] = fmaf(w4[i].y, x4[1].w, acc[i][3]);
                acc[i][0] = fmaf(w4[i].z, x4[2].x, acc[i][0]);
                acc[i][1] = fmaf(w4[i].z, x4[2].y, acc[i][1]);
                acc[i][2] = fmaf(w4[i].z, x4[2].z, acc[i][2]);
                acc[i][3] = fmaf(w4[i].z, x4[2].w, acc[i][3]);
                acc[i][0] = fmaf(w4[i].w, x4[3].x, acc[i][0]);
                acc[i][1] = fmaf(w4[i].w, x4[3].y, acc[i][1]);
                acc[i][2] = fmaf(w4[i].w, x4[3].z, acc[i][2]);
                acc[i][3] = fmaf(w4[i].w, x4[3].w, acc[i][3]);
            }
        }

#pragma unroll
        for (int i = 0; i < 4; ++i) {
            const float4 st = make_float4(acc[i][0], acc[i][1], acc[i][2], acc[i][3]);
            *(float4*)(osel + (obase + i) * SP + p0 + pbase) = st;
        }
    }
}

// DPP cross-lane shifts within 16-lane rows; bound_ctrl=1 -> out-of-row
// source reads 0, which exactly matches the w-boundary zero-pad (wg==0 /
// wg==15 are DPP row boundaries).
__device__ __forceinline__ float dpp_shr1(float x) {   // lane i <- lane i-1
    return __int_as_float(__builtin_amdgcn_mov_dpp(__float_as_int(x), 0x111, 0xf, 0xf, true));
}
__device__ __forceinline__ float dpp_shl1(float x) {   // lane i <- lane i+1
    return __int_as_float(__builtin_amdgcn_mov_dpp(__float_as_int(x), 0x101, 0xf, 0xf, true));
}

// attn, LDS-tiled: block = (o, dtile, htile) covering 8d x 8h x 64w outputs.
// Stage k,v halo tiles [10][10][64] into LDS in one batched burst, then
// all-LDS compute: thread = 4d x 4w outputs, per (dp,hp) row one
// ds_read_b128 each for k,v; w-edges via DPP shifts (zero LDS cost).
// Single-pass softmax (logits bounded); OOB: k=0+rel in softmax, v=0.
template<int AXIS>
__global__ __launch_bounds__(256) void attn(const float* __restrict__ kbuf,
                                            const float* __restrict__ vbuf,
                                            const float* __restrict__ qbuf,
                                            const float* __restrict__ rel,
                                            float* __restrict__ out,
                                            int obase_band) {
    __shared__ float kt[100 * 64];   // [dp][hp][w] halo'd, 25.6 KB
    __shared__ float vt[100 * 64];

    const int dt = blockIdx.x;       // 0..1
    const int ht = blockIdx.y;       // 0..7
    const int ob = blockIdx.z;       // channel within band
    const int o  = obase_band + ob;

    const int d0 = dt * 8;
    const int h0 = ht * 8;
    const int t  = threadIdx.x;

    const float* __restrict__ kc = kbuf + o * SP;
    const float* __restrict__ vc = vbuf + o * SP;

    const float r0 = rel[ob * 3 + 0];
    const float r1 = rel[ob * 3 + 1];
    const float r2 = rel[ob * 3 + 2];

    // ---- stage k,v halo tiles: 2 * 100 rows * 16 float4 = 3200 float4 ----
#pragma unroll
    for (int i = 0; i < 13; ++i) {
        const int idx = t + 256 * i;
        if (idx < 3200) {
            const bool isv = idx >= 1600;
            const int rem  = isv ? idx - 1600 : idx;
            const int row  = rem >> 4;         // 0..99
            const int j    = rem & 15;
            const int dp   = row / 10;
            const int hp   = row - dp * 10;
            const int dpg  = d0 - 1 + dp;
            const int hpg  = h0 - 1 + hp;
            float4 val = make_float4(0.f, 0.f, 0.f, 0.f);
            if ((unsigned)dpg < (unsigned)DD && (unsigned)hpg < (unsigned)HH) {
                const float* src = (isv ? vc : kc) + (dpg * HH + hpg) * WW + j * 4;
                val = *(const float4*)src;
            }
            *(float4*)((isv ? vt : kt) + row * 64 + j * 4) = val;
        }
    }

    // ---- thread decomposition: wg (4w) x h x dg (4d) ----
    const int wg = t & 15;
    const int h  = (t >> 4) & 7;
    const int dg = t >> 7;           // 0 or 1

    float qs[4][4];                  // [di][wi]
#pragma unroll
    for (int di = 0; di < 4; ++di) {
        const int dabs = d0 + dg * 4 + di;
        const float4 q4 = *(const float4*)(qbuf + o * SP + (dabs * HH + (h0 + h)) * WW + wg * 4);
        qs[di][0] = q4.x; qs[di][1] = q4.y; qs[di][2] = q4.z; qs[di][3] = q4.w;
    }

    __syncthreads();

    float s[4][4] = {};
    float a[4][4] = {};

#pragma unroll 1
    for (int m = 0; m < 6; ++m) {          // halo dp = dg*4 + m
#pragma unroll 1
        for (int kh = 0; kh < 3; ++kh) {
            const int row = (dg * 4 + m) * 10 + (h + kh);
            const float4 km = *(const float4*)(kt + row * 64 + wg * 4);
            const float4 vm = *(const float4*)(vt + row * 64 + wg * 4);
            const float kl = dpp_shr1(km.w), kr = dpp_shl1(km.x);
            const float vl = dpp_shr1(vm.w), vr = dpp_shl1(vm.x);
            const float krow[6] = { kl, km.x, km.y, km.z, km.w, kr };
            const float vrow[6] = { vl, vm.x, vm.y, vm.z, vm.w, vr };

            const float rkh = (kh == 0) ? r0 : (kh == 1) ? r1 : r2;

#pragma unroll
            for (int di = 0; di < 4; ++di) {
                const int kd = m - di;          // uniform guard
                if ((unsigned)kd < 3u) {
                    const float rdd = (kd == 0) ? r0 : (kd == 1) ? r1 : r2;
                    const float rr  = (AXIS == 0) ? rdd : (AXIS == 1) ? rkh : 0.f;
#pragma unroll
                    for (int wi = 0; wi < 4; ++wi) {
                        const float qv = qs[di][wi];
#pragma unroll
                        for (int kw = 0; kw < 3; ++kw) {
                            const float rc = (AXIS == 2)
                                           ? ((kw == 0) ? r0 : (kw == 1) ? r1 : r2)
                                           : rr;
                            const float e = __expf(qv * (krow[wi + kw] + rc));
                            s[di][wi] += e;
                            a[di][wi] = fmaf(e, vrow[wi + kw], a[di][wi]);
                        }
                    }
                }
            }
        }
    }

#pragma unroll
    for (int di = 0; di < 4; ++di) {
        const int dabs = d0 + dg * 4 + di;
        float4 ov;
        ov.x = a[di][0] * __builtin_amdgcn_rcpf(s[di][0]);
        ov.y = a[di][1] * __builtin_amdgcn_rcpf(s[di][1]);
        ov.z = a[di][2] * __builtin_amdgcn_rcpf(s[di][2]);
        ov.w = a[di][3] * __builtin_amdgcn_rcpf(s[di][3]);
        *(float4*)(out + o * SP + (dabs * HH + (h0 + h)) * WW + wg * 4) = ov;
    }
}

extern "C" void kernel_launch(void* const* d_in, const int* in_sizes, int n_in,
                              void* d_out, int out_size, void* d_ws, size_t ws_size,
                              hipStream_t stream) {
    const float* x     = (const float*)d_in[0];
    const float* w_q   = (const float*)d_in[1];
    const float* w_k   = (const float*)d_in[2];
    const float* w_v   = (const float*)d_in[3];
    const float* rel_d = (const float*)d_in[4];
    const float* rel_h = (const float*)d_in[5];
    const float* rel_w = (const float*)d_in[6];
    float* out = (float*)d_out;

    float* ws = (float*)d_ws;
    float* q  = ws;
    float* k  = ws + (size_t)COUT * SP;
    float* v  = ws + 2 * (size_t)COUT * SP;

    proj<<<SP / 64, 256, 0, stream>>>(x, w_q, w_k, w_v, q, k, v);

    // three channel bands by rel axis: [0,21) d, [21,42) h, [42,64) w
    attn<0><<<dim3(2, 8, 21), 256, 0, stream>>>(k, v, q, rel_d, out, 0);
    attn<1><<<dim3(2, 8, 21), 256, 0, stream>>>(k, v, q, rel_h, out, 21);
    attn<2><<<dim3(2, 8, 22), 256, 0, stream>>>(k, v, q, rel_w, out, 42);
}

// Round 8
// 128.689 us; speedup vs baseline: 1.5929x; 1.1960x over previous
//
#include <hip/hip_runtime.h>

#define SP    65536      // 16*64*64 spatial voxels
#define DD    16
#define HH    64
#define WW    64
#define CIN   64
#define COUT  64

#define XPAD  68         // proj LDS row pitch (68%32=4 -> adjacent rows offset 4 banks)

// ws layout (fp32): q [64][SP] | k [64][SP] | v [64][SP]   (48 MB total)

// proj: LDS GEMM, ONE matrix per block (grid 1024 x 3). Stage x tile
// [64c][64p] + one weight matrix [64o][64c], single barrier, compute
// 4o x 4p per thread, store, end. vs round-6/7: no weight restaging, no
// mid-kernel vmcnt(0) store-drains at barriers (6 syncs -> 1).
__global__ __launch_bounds__(256) void proj(const float* __restrict__ x,
                                            const float* __restrict__ wq,
                                            const float* __restrict__ wk,
                                            const float* __restrict__ wv,
                                            float* __restrict__ q,
                                            float* __restrict__ k,
                                            float* __restrict__ v) {
    __shared__ float xl[CIN][XPAD];    // [c][p]
    __shared__ float wl[COUT][XPAD];   // [o][c]

    const int t  = threadIdx.x;
    const int p0 = blockIdx.x * 64;
    const int m  = blockIdx.y;

    const float* __restrict__ wsel = (m == 0) ? wq : (m == 1) ? wk : wv;
    float* __restrict__       osel = (m == 0) ? q  : (m == 1) ? k  : v;

    // stage x tile (1024 float4) and weight matrix (1024 float4)
#pragma unroll
    for (int i = 0; i < 4; ++i) {
        const int f = t + 256 * i;
        const int c = f >> 4, j = f & 15;
        *(float4*)(&xl[c][j * 4]) = *(const float4*)(x + c * SP + p0 + j * 4);
    }
#pragma unroll
    for (int i = 0; i < 4; ++i) {
        const int f = t + 256 * i;
        const int o = f >> 4, j = f & 15;
        *(float4*)(&wl[o][j * 4]) = *(const float4*)(wsel + o * CIN + j * 4);
    }
    __syncthreads();

    const int og    = t >> 4;
    const int pg    = t & 15;
    const int obase = og * 4;
    const int pbase = pg * 4;

    float acc[4][4] = {};
#pragma unroll
    for (int c4 = 0; c4 < CIN / 4; ++c4) {
        float4 w4[4], x4[4];
#pragma unroll
        for (int i = 0; i < 4; ++i)
            w4[i] = *(const float4*)(&wl[obase + i][c4 * 4]);
#pragma unroll
        for (int cc = 0; cc < 4; ++cc)
            x4[cc] = *(const float4*)(&xl[c4 * 4 + cc][pbase]);
#pragma unroll
        for (int i = 0; i < 4; ++i) {
            acc[i][0] = fmaf(w4[i].x, x4[0].x, acc[i][0]);
            acc[i][1] = fmaf(w4[i].x, x4[0].y, acc[i][1]);
            acc[i][2] = fmaf(w4[i].x, x4[0].z, acc[i][2]);
            acc[i][3] = fmaf(w4[i].x, x4[0].w, acc[i][3]);
            acc[i][0] = fmaf(w4[i].y, x4[1].x, acc[i][0]);
            acc[i][1] = fmaf(w4[i].y, x4[1].y, acc[i][1]);
            acc[i][2] = fmaf(w4[i].y, x4[1].z, acc[i][2]);
            acc[i][3] = fmaf(w4[i].y, x4[1].w, acc[i][3]);
            acc[i][0] = fmaf(w4[i].z, x4[2].x, acc[i][0]);
            acc[i][1] = fmaf(w4[i].z, x4[2].y, acc[i][1]);
            acc[i][2] = fmaf(w4[i].z, x4[2].z, acc[i][2]);
            acc[i][3] = fmaf(w4[i].z, x4[2].w, acc[i][3]);
            acc[i][0] = fmaf(w4[i].w, x4[3].x, acc[i][0]);
            acc[i][1] = fmaf(w4[i].w, x4[3].y, acc[i][1]);
            acc[i][2] = fmaf(w4[i].w, x4[3].z, acc[i][2]);
            acc[i][3] = fmaf(w4[i].w, x4[3].w, acc[i][3]);
        }
    }

#pragma unroll
    for (int i = 0; i < 4; ++i) {
        const float4 st = make_float4(acc[i][0], acc[i][1], acc[i][2], acc[i][3]);
        *(float4*)(osel + (obase + i) * SP + p0 + pbase) = st;
    }
}

// DPP cross-lane shifts within 16-lane rows; bound_ctrl=1 -> out-of-row
// source reads 0, matching the w-boundary zero-pad (wg==0/15 are DPP row
// boundaries).
__device__ __forceinline__ float dpp_shr1(float x) {   // lane i <- lane i-1
    return __int_as_float(__builtin_amdgcn_mov_dpp(__float_as_int(x), 0x111, 0xf, 0xf, true));
}
__device__ __forceinline__ float dpp_shl1(float x) {   // lane i <- lane i+1
    return __int_as_float(__builtin_amdgcn_mov_dpp(__float_as_int(x), 0x101, 0xf, 0xf, true));
}

// axis-specialized compute over the staged LDS tiles
template<int AXIS>
__device__ __forceinline__ void attn_compute(const float* __restrict__ kt,
                                             const float* __restrict__ vt,
                                             const float (&qs)[4][4],
                                             float r0, float r1, float r2,
                                             int wg, int h, int dg,
                                             float (&s)[4][4], float (&a)[4][4]) {
#pragma unroll 1
    for (int m = 0; m < 6; ++m) {          // halo dp = dg*4 + m
#pragma unroll 1
        for (int kh = 0; kh < 3; ++kh) {
            const int row = (dg * 4 + m) * 10 + (h + kh);
            const float4 km = *(const float4*)(kt + row * 64 + wg * 4);
            const float4 vm = *(const float4*)(vt + row * 64 + wg * 4);
            const float kl = dpp_shr1(km.w), kr = dpp_shl1(km.x);
            const float vl = dpp_shr1(vm.w), vr = dpp_shl1(vm.x);
            const float krow[6] = { kl, km.x, km.y, km.z, km.w, kr };
            const float vrow[6] = { vl, vm.x, vm.y, vm.z, vm.w, vr };

            const float rkh = (kh == 0) ? r0 : (kh == 1) ? r1 : r2;

#pragma unroll
            for (int di = 0; di < 4; ++di) {
                const int kd = m - di;
                if ((unsigned)kd < 3u) {
                    const float rdd = (kd == 0) ? r0 : (kd == 1) ? r1 : r2;
                    const float rr  = (AXIS == 0) ? rdd : (AXIS == 1) ? rkh : 0.f;
#pragma unroll
                    for (int wi = 0; wi < 4; ++wi) {
                        const float qv = qs[di][wi];
#pragma unroll
                        for (int kw = 0; kw < 3; ++kw) {
                            const float rc = (AXIS == 2)
                                           ? ((kw == 0) ? r0 : (kw == 1) ? r1 : r2)
                                           : rr;
                            const float e = __expf(qv * (krow[wi + kw] + rc));
                            s[di][wi] += e;
                            a[di][wi] = fmaf(e, vrow[wi + kw], a[di][wi]);
                        }
                    }
                }
            }
        }
    }
}

// attn, LDS-tiled, SINGLE launch: block = (dtile, htile, o) covering
// 8d x 8h x 64w outputs of one channel. Stage k,v halo tiles [10][10][64],
// one barrier, all-LDS compute (thread = 4d x 4w), axis picked by a
// block-uniform branch. Single-pass softmax (logits bounded); OOB: k=0+rel
// stays in softmax, v=0.
__global__ __launch_bounds__(256) void attn(const float* __restrict__ kbuf,
                                            const float* __restrict__ vbuf,
                                            const float* __restrict__ qbuf,
                                            const float* __restrict__ rel_d,
                                            const float* __restrict__ rel_h,
                                            const float* __restrict__ rel_w,
                                            float* __restrict__ out) {
    __shared__ float kt[100 * 64];   // [dp][hp][w] halo'd, 25.6 KB
    __shared__ float vt[100 * 64];

    const int dt = blockIdx.x;       // 0..1
    const int ht = blockIdx.y;       // 0..7
    const int o  = blockIdx.z;       // 0..63

    const int d0 = dt * 8;
    const int h0 = ht * 8;
    const int t  = threadIdx.x;

    const float* __restrict__ kc = kbuf + o * SP;
    const float* __restrict__ vc = vbuf + o * SP;

    // ---- stage k,v halo tiles: 2 * 100 rows * 16 float4 ----
#pragma unroll
    for (int i = 0; i < 13; ++i) {
        const int idx = t + 256 * i;
        if (idx < 3200) {
            const bool isv = idx >= 1600;
            const int rem  = isv ? idx - 1600 : idx;
            const int row  = rem >> 4;
            const int j    = rem & 15;
            const int dp   = row / 10;
            const int hp   = row - dp * 10;
            const int dpg  = d0 - 1 + dp;
            const int hpg  = h0 - 1 + hp;
            float4 val = make_float4(0.f, 0.f, 0.f, 0.f);
            if ((unsigned)dpg < (unsigned)DD && (unsigned)hpg < (unsigned)HH) {
                const float* src = (isv ? vc : kc) + (dpg * HH + hpg) * WW + j * 4;
                val = *(const float4*)src;
            }
            *(float4*)((isv ? vt : kt) + row * 64 + j * 4) = val;
        }
    }

    const int wg = t & 15;
    const int h  = (t >> 4) & 7;
    const int dg = t >> 7;

    float qs[4][4];
#pragma unroll
    for (int di = 0; di < 4; ++di) {
        const int dabs = d0 + dg * 4 + di;
        const float4 q4 = *(const float4*)(qbuf + o * SP + (dabs * HH + (h0 + h)) * WW + wg * 4);
        qs[di][0] = q4.x; qs[di][1] = q4.y; qs[di][2] = q4.z; qs[di][3] = q4.w;
    }

    __syncthreads();

    float s[4][4] = {};
    float a[4][4] = {};

    if (o < 21) {
        attn_compute<0>(kt, vt, qs, rel_d[o * 3 + 0], rel_d[o * 3 + 1], rel_d[o * 3 + 2],
                        wg, h, dg, s, a);
    } else if (o < 42) {
        const int b = o - 21;
        attn_compute<1>(kt, vt, qs, rel_h[b * 3 + 0], rel_h[b * 3 + 1], rel_h[b * 3 + 2],
                        wg, h, dg, s, a);
    } else {
        const int b = o - 42;
        attn_compute<2>(kt, vt, qs, rel_w[b * 3 + 0], rel_w[b * 3 + 1], rel_w[b * 3 + 2],
                        wg, h, dg, s, a);
    }

#pragma unroll
    for (int di = 0; di < 4; ++di) {
        const int dabs = d0 + dg * 4 + di;
        float4 ov;
        ov.x = a[di][0] * __builtin_amdgcn_rcpf(s[di][0]);
        ov.y = a[di][1] * __builtin_amdgcn_rcpf(s[di][1]);
        ov.z = a[di][2] * __builtin_amdgcn_rcpf(s[di][2]);
        ov.w = a[di][3] * __builtin_amdgcn_rcpf(s[di][3]);
        *(float4*)(out + o * SP + (dabs * HH + (h0 + h)) * WW + wg * 4) = ov;
    }
}

extern "C" void kernel_launch(void* const* d_in, const int* in_sizes, int n_in,
                              void* d_out, int out_size, void* d_ws, size_t ws_size,
                              hipStream_t stream) {
    const float* x     = (const float*)d_in[0];
    const float* w_q   = (const float*)d_in[1];
    const float* w_k   = (const float*)d_in[2];
    const float* w_v   = (const float*)d_in[3];
    const float* rel_d = (const float*)d_in[4];
    const float* rel_h = (const float*)d_in[5];
    const float* rel_w = (const float*)d_in[6];
    float* out = (float*)d_out;

    float* ws = (float*)d_ws;
    float* q  = ws;
    float* k  = ws + (size_t)COUT * SP;
    float* v  = ws + 2 * (size_t)COUT * SP;

    proj<<<dim3(SP / 64, 3), 256, 0, stream>>>(x, w_q, w_k, w_v, q, k, v);
    attn<<<dim3(2, 8, 64), 256, 0, stream>>>(k, v, q, rel_d, rel_h, rel_w, out);
}